// Round 2
// baseline (175.037 us; speedup 1.0000x reference)
//
#include <hip/hip_runtime.h>
#include <math.h>

// ---- compile-time physical constants (mirror the Python reference) ----
namespace k {
constexpr double dA     = 0.129907 + 0.095724;       // L_X + L_Y
constexpr double dR     = 4.0 * 0.0254;              // wheel radius
constexpr double dI     = 6.0;                       // inertia (== mass)
constexpr double dMOI   = 6.0 * (12.0 * 0.0254) * (12.0 * 0.0254) / 6.0;
constexpr float T_STALL   = (float)(5.4 / 100.0);
constexpr float INV_WFREE = (float)(1.0 / (1620.0 / 60.0 * 2.0 * 3.14159265358979323846));
constexpr float A         = (float)dA;
constexpr float INV_R     = (float)(1.0 / dR);
constexpr float INV_RI    = (float)(1.0 / (dR * dI));    // WT2LA rows 0,1 scale
constexpr float A_RMOI    = (float)(dA / (dR * dMOI));   // WT2LA row 2 scale
}

// native clang vector type: required by __builtin_nontemporal_store
// (HIP_vector_type<float,4> is a struct and is rejected). Same 16 B layout.
typedef float f32x4 __attribute__((ext_vector_type(4)));

__device__ __forceinline__ float wheel_torque(float w, float m) {
    float p = m * w;
    // jnp.sign semantics: sign(0)=0 -> is_same_direction = 0.5
    float sgn = (float)(p > 0.0f) - (float)(p < 0.0f);
    float isd = 0.5f * (sgn + 1.0f);
    return k::T_STALL * (1.0f - fabsf(w) * isd * k::INV_WFREE) * m;
}

// One batch element: st[0..5] = state row, m0..m3 = motor duty, o[0..5] = out row
__device__ __forceinline__ void mecanum_elem(const float st[6],
                                             float m0, float m1, float m2, float m3,
                                             float o[6]) {
    float theta = st[2];
    float s, c;
    sincosf(theta, &s, &c);

    float v0 = st[3], v1 = st[4], v2 = st[5];

    // a2l = rot(cos(-t), sin(-t)) -> [[c, s, 0], [-s, c, 0], [0,0,1]]
    float lv0 = c * v0 + s * v1;
    float lv1 = c * v1 - s * v0;

    // wheel_vel = LV2WV @ local_vel; rows [1,-1,-A],[1,1,A],[1,1,-A],[1,-1,A], /R
    float al2 = k::A * v2;
    float w0 = (lv0 - lv1 - al2) * k::INV_R;
    float w1 = (lv0 + lv1 + al2) * k::INV_R;
    float w2 = (lv0 + lv1 - al2) * k::INV_R;
    float w3 = (lv0 - lv1 + al2) * k::INV_R;

    float t0 = wheel_torque(w0, m0);
    float t1 = wheel_torque(w1, m1);
    float t2 = wheel_torque(w2, m2);
    float t3 = wheel_torque(w3, m3);

    // local_accel = WT2LA @ torque
    float la0 = (t0 + t1 + t2 + t3) * k::INV_RI;
    float la1 = (-t0 + t1 + t2 - t3) * k::INV_RI;
    float la2 = (-t0 + t1 - t2 + t3) * k::A_RMOI;

    // l2a = rot(cos(t), sin(t)) -> [[c,-s,0],[s,c,0],[0,0,1]]
    float aa0 = c * la0 - s * la1;
    float aa1 = s * la0 + c * la1;

    o[0] = st[3]; o[1] = st[4]; o[2] = st[5];
    o[3] = aa0; o[4] = aa1; o[5] = la2;
}

// ---------------------------------------------------------------------------
// Wave-autonomous version: each 64-lane wave owns a private 192-float4 (3 KB)
// LDS slice and never synchronizes with other waves.  No __syncthreads().
//
// Correctness of barrier-free LDS exchange:
//   - A CDNA wave is lockstep (one PC); the LDS pipeline processes a wave's
//     DS ops in program order. So phase-1 writes (s[ws+64r+lane]) are ordered
//     before phase-2 reads (s[ws+3*lane+j]) for ALL lanes by instruction
//     order alone; same for phase-2 writes -> phase-3 reads.
//   - Phase-2 is in-place: lane l reads and writes exactly s[ws+3l+{0,1,2}],
//     so the only cross-lane aliasing (3l+j == 3u+j  =>  l==u) is the lane's
//     own address — no cross-lane WAR hazard regardless of scheduling.
//   - wave_barrier + memory-clobber asm pin the compiler's scheduler at the
//     two phase boundaries (belt and braces; per-thread alias analysis
//     cannot disprove 64r+l == 3l+j either, so order is kept anyway).
//
// LDS: single reused 12,288 B buffer (was 2x12 KB) -> thread cap (2048/CU)
// becomes the occupancy limit: 8 blocks/CU, 32 waves/CU (100%), vs 49% before.
// ---------------------------------------------------------------------------
#define PAIRS_PER_BLOCK 256
#define F4_PER_BLOCK    (PAIRS_PER_BLOCK * 3)

__global__ __launch_bounds__(256, 8) void mecanum_wave_kernel(
    const float4* __restrict__ state4,
    const float* __restrict__ cd,
    float4* __restrict__ out4,
    int n_pairs) {
    __shared__ float4 s[F4_PER_BLOCK];   // 12 KB, 192 float4 per wave

    const int tid  = threadIdx.x;
    const int wave = tid >> 6;
    const int lane = tid & 63;
    const int pair_base = blockIdx.x * PAIRS_PER_BLOCK;
    const int f4_base   = pair_base * 3;
    const int total4    = n_pairs * 3;
    const int ws = wave * 192;           // this wave's float4 slice base

    // batch-uniform motor duty: CD2MD @ control_duty (scalar loads)
    float u0 = cd[0], u1 = cd[1], u2 = cd[2];
    float m0 = u0 - u1 - u2;
    float m1 = u0 + u1 + u2;
    float m2 = u0 + u1 - u2;
    float m3 = u0 - u1 + u2;

    // ---- phase 1: coalesced load, lane-consecutive float4, into wave slice
#pragma unroll
    for (int r = 0; r < 3; ++r) {
        int g = f4_base + ws + r * 64 + lane;
        if (g < total4) s[ws + r * 64 + lane] = state4[g];
    }
    __builtin_amdgcn_wave_barrier();
    asm volatile("" ::: "memory");

    // ---- phase 2: gather this lane's element pair, compute, write back
    if (pair_base + wave * 64 + lane < n_pairs) {
        float4 a  = s[ws + 3 * lane + 0];
        float4 b  = s[ws + 3 * lane + 1];
        float4 g4 = s[ws + 3 * lane + 2];

        float stA[6] = { a.x, a.y, a.z, a.w, b.x, b.y };
        float stB[6] = { b.z, b.w, g4.x, g4.y, g4.z, g4.w };
        float oA[6], oB[6];
        mecanum_elem(stA, m0, m1, m2, m3, oA);
        mecanum_elem(stB, m0, m1, m2, m3, oB);

        s[ws + 3 * lane + 0] = make_float4(oA[0], oA[1], oA[2], oA[3]);
        s[ws + 3 * lane + 1] = make_float4(oA[4], oA[5], oB[0], oB[1]);
        s[ws + 3 * lane + 2] = make_float4(oB[2], oB[3], oB[4], oB[5]);
    }
    __builtin_amdgcn_wave_barrier();
    asm volatile("" ::: "memory");

    // ---- phase 3: coalesced nontemporal store (output is write-only;
    //      keep the L3 for the input stream, which it already half-serves)
#pragma unroll
    for (int r = 0; r < 3; ++r) {
        int idx = ws + r * 64 + lane;
        int g = f4_base + idx;
        if (g < total4) {
            f32x4 v;
            float4 t = s[idx];
            v.x = t.x; v.y = t.y; v.z = t.z; v.w = t.w;
            __builtin_nontemporal_store(v, (f32x4*)&out4[g]);
        }
    }
}

// Scalar tail for odd batch sizes (defensive; BATCH=4M is even).
__global__ void mecanum_tail_kernel(const float* __restrict__ state,
                                    const float* __restrict__ cd,
                                    float* __restrict__ out,
                                    int start, int n) {
    int i = start + blockIdx.x * blockDim.x + threadIdx.x;
    if (i >= n) return;
    float u0 = cd[0], u1 = cd[1], u2 = cd[2];
    float m0 = u0 - u1 - u2;
    float m1 = u0 + u1 + u2;
    float m2 = u0 + u1 - u2;
    float m3 = u0 - u1 + u2;
    float st[6], o[6];
#pragma unroll
    for (int j = 0; j < 6; ++j) st[j] = state[6 * i + j];
    mecanum_elem(st, m0, m1, m2, m3, o);
#pragma unroll
    for (int j = 0; j < 6; ++j) out[6 * i + j] = o[j];
}

extern "C" void kernel_launch(void* const* d_in, const int* in_sizes, int n_in,
                              void* d_out, int out_size, void* d_ws, size_t ws_size,
                              hipStream_t stream) {
    // inputs: d_in[0] = t (1, unused), d_in[1] = state (BATCH*6), d_in[2] = control_duty (3)
    const float* state = (const float*)d_in[1];
    const float* cd    = (const float*)d_in[2];
    float* out         = (float*)d_out;

    int n = in_sizes[1] / 6;        // batch size
    int n_pairs = n / 2;

    if (n_pairs > 0) {
        int grid = (n_pairs + PAIRS_PER_BLOCK - 1) / PAIRS_PER_BLOCK;
        mecanum_wave_kernel<<<grid, 256, 0, stream>>>(
            (const float4*)state, cd, (float4*)out, n_pairs);
    }
    if (n & 1) {
        mecanum_tail_kernel<<<1, 64, 0, stream>>>(state, cd, out, 2 * n_pairs, n);
    }
}